// Round 2
// baseline (803.241 us; speedup 1.0000x reference)
//
#include <hip/hip_runtime.h>
#include <hip/hip_bf16.h>
#include <math.h>

#define BATCH 4
#define HEADS 16
#define SEQ   2048
#define DIM   128
#define BHN   (BATCH*HEADS)

#define BQ 128   // q rows per block
#define WQ 32    // q rows per wave (2 MFMA M-blocks)
#define KT 32    // k rows per stage/compute tile

typedef short bf16x8 __attribute__((ext_vector_type(8)));
typedef float f32x4  __attribute__((ext_vector_type(4)));

static __device__ __forceinline__ unsigned short f2bf(float f) {
    union { float f; unsigned u; } x; x.f = f;
    unsigned r = x.u + 0x7FFF + ((x.u >> 16) & 1);  // RNE
    return (unsigned short)(r >> 16);
}

// ---------------- K: fp32 -> bf16, layout unchanged ----------------
__global__ __launch_bounds__(256) void cvt_k(const float* __restrict__ k,
                                             unsigned short* __restrict__ kb) {
    long e = ((long)blockIdx.x * 256 + threadIdx.x) * 8;
    float4 a0 = *(const float4*)(k + e);
    float4 a1 = *(const float4*)(k + e + 4);
    union { uint4 u; unsigned short s[8]; } p;
    p.s[0]=f2bf(a0.x); p.s[1]=f2bf(a0.y); p.s[2]=f2bf(a0.z); p.s[3]=f2bf(a0.w);
    p.s[4]=f2bf(a1.x); p.s[5]=f2bf(a1.y); p.s[6]=f2bf(a1.z); p.s[7]=f2bf(a1.w);
    *(uint4*)(kb + e) = p.u;
}

// ---------------- V: fp32 -> bf16 + per-head transpose: vt[bh][d][s] ----------------
__global__ __launch_bounds__(256) void cvt_vt(const float* __restrict__ v,
                                              unsigned short* __restrict__ vt) {
    __shared__ unsigned short T[DIM][72];   // 64 s-rows staged transposed; stride 144B
    const int bh = blockIdx.y;
    const int s0 = blockIdx.x * 64;
    const int t  = threadIdx.x;
    {
        const int r = t >> 2, i = t & 3;    // r: s-row 0..63, i: 32-col group
        const float* src = v + ((long)bh * SEQ + s0 + r) * DIM + i * 32;
        #pragma unroll
        for (int j = 0; j < 8; ++j) {
            float4 x = *(const float4*)(src + j * 4);
            const int d = i * 32 + j * 4;
            T[d + 0][r] = f2bf(x.x); T[d + 1][r] = f2bf(x.y);
            T[d + 2][r] = f2bf(x.z); T[d + 3][r] = f2bf(x.w);
        }
    }
    __syncthreads();
    {
        const int d = t >> 1, h = t & 1;
        unsigned short* dst = vt + ((long)bh * DIM + d) * SEQ + s0 + h * 32;
        #pragma unroll
        for (int m = 0; m < 4; ++m)
            *(uint4*)(dst + m * 8) = *(const uint4*)&T[d][h * 32 + m * 8];
    }
}

// ---------------- flash attention ----------------
__global__ __launch_bounds__(256, 3) void attn_fwd(
    const float* __restrict__ qg,
    const unsigned short* __restrict__ kb,
    const unsigned short* __restrict__ vtg,
    float* __restrict__ out) {

    __shared__ unsigned short Kt[2][KT][DIM + 8];   // 2 x 32 x 136  (row 272B, 16B-mult)
    __shared__ unsigned short Vt[2][DIM][KT + 8];   // 2 x 128 x 40  (row 80B, 16B-mult)
    __shared__ unsigned short Pl[4][16][KT + 8];    // per-wave P tile [q][k]

    const int tid  = threadIdx.x;
    const int w    = tid >> 6;
    const int lane = tid & 63;
    const int quad = lane >> 4;
    const int ql   = lane & 15;

    const int bh  = blockIdx.y;
    const int xb  = gridDim.x - 1 - blockIdx.x;    // long (diagonal-heavy) blocks first
    const int qb0 = xb * BQ;
    const int qw0 = qb0 + w * WQ;

    const long base = (long)bh * SEQ * DIM;        // q, kb, out (and vt: DIM*SEQ == SEQ*DIM)
    const float scale = 0.08838834764831845f;      // 1/sqrt(128), folded into Q

    // ---- Q fragments (B-operand for Sc = K*Q^T), pre-scaled ----
    bf16x8 qf[2][4];
    #pragma unroll
    for (int mb = 0; mb < 2; ++mb) {
        const float* qr = qg + base + (long)(qw0 + mb * 16 + ql) * DIM;
        #pragma unroll
        for (int c = 0; c < 4; ++c) {
            const float* p = qr + c * 32 + quad * 8;
            float4 x = *(const float4*)(p);
            float4 y = *(const float4*)(p + 4);
            union { bf16x8 v; unsigned short s[8]; } u;
            u.s[0]=f2bf(x.x*scale); u.s[1]=f2bf(x.y*scale);
            u.s[2]=f2bf(x.z*scale); u.s[3]=f2bf(x.w*scale);
            u.s[4]=f2bf(y.x*scale); u.s[5]=f2bf(y.y*scale);
            u.s[6]=f2bf(y.z*scale); u.s[7]=f2bf(y.w*scale);
            qf[mb][c] = u.v;
        }
    }

    f32x4 acc[2][8];
    #pragma unroll
    for (int mb = 0; mb < 2; ++mb)
        #pragma unroll
        for (int n = 0; n < 8; ++n)
            acc[mb][n] = (f32x4){0.f, 0.f, 0.f, 0.f};

    float m_[2] = {-INFINITY, -INFINITY};
    float l_[2] = {0.f, 0.f};

    uint4 kpre[2], vpre[2];
    auto load_tile = [&](int k0) {
        #pragma unroll
        for (int i = 0; i < 2; ++i) {
            int idx = tid + i * 256;
            kpre[i] = *(const uint4*)(kb  + base + (long)(k0 + (idx >> 4)) * DIM + (idx & 15) * 8);
            vpre[i] = *(const uint4*)(vtg + base + (long)(idx >> 2) * SEQ + k0 + (idx & 3) * 8);
        }
    };
    auto store_tile = [&](int buf) {
        #pragma unroll
        for (int i = 0; i < 2; ++i) {
            int idx = tid + i * 256;
            *(uint4*)&Kt[buf][idx >> 4][(idx & 15) * 8] = kpre[i];
            *(uint4*)&Vt[buf][idx >> 2][(idx & 3) * 8]  = vpre[i];
        }
    };

    const int ntile = (qb0 + BQ) / KT;

    load_tile(0);
    store_tile(0);

    for (int t = 0; t < ntile; ++t) {
        const int buf = t & 1;
        const int k0  = t * KT;
        __syncthreads();                 // tile t visible; prev tile's readers done

        if (t + 1 < ntile) load_tile(k0 + KT);   // in flight during compute

        const bool active = (k0 < qw0 + WQ);
        if (active) {
            // ---- Sc = K * Q^T  (rows=k, cols=q) ----
            f32x4 sacc[2][2];
            #pragma unroll
            for (int mb = 0; mb < 2; ++mb)
                #pragma unroll
                for (int kk = 0; kk < 2; ++kk)
                    sacc[mb][kk] = (f32x4){0.f, 0.f, 0.f, 0.f};
            #pragma unroll
            for (int c = 0; c < 4; ++c) {
                bf16x8 kf0 = *(const bf16x8*)&Kt[buf][ql]     [c * 32 + quad * 8];
                bf16x8 kf1 = *(const bf16x8*)&Kt[buf][16 + ql][c * 32 + quad * 8];
                #pragma unroll
                for (int mb = 0; mb < 2; ++mb) {
                    sacc[mb][0] = __builtin_amdgcn_mfma_f32_16x16x32_bf16(kf0, qf[mb][c], sacc[mb][0], 0, 0, 0);
                    sacc[mb][1] = __builtin_amdgcn_mfma_f32_16x16x32_bf16(kf1, qf[mb][c], sacc[mb][1], 0, 0, 0);
                }
            }

            // V fragments (shared across mb)
            bf16x8 vf[8];
            #pragma unroll
            for (int n = 0; n < 8; ++n)
                vf[n] = *(const bf16x8*)&Vt[buf][n * 16 + ql][quad * 8];

            #pragma unroll
            for (int mb = 0; mb < 2; ++mb) {
                const int qrow  = qw0 + mb * 16 + ql;
                const bool needm = (k0 + KT - 1 > qw0 + mb * 16);  // wave-uniform
                float s[2][4];
                float tmax = -INFINITY;
                #pragma unroll
                for (int kk = 0; kk < 2; ++kk)
                    #pragma unroll
                    for (int r = 0; r < 4; ++r) {
                        float sv = sacc[mb][kk][r];
                        if (needm) {
                            int kg = k0 + kk * 16 + quad * 4 + r;
                            sv = (kg <= qrow) ? sv : -INFINITY;
                        }
                        s[kk][r] = sv;
                        tmax = fmaxf(tmax, sv);
                    }
                tmax = fmaxf(tmax, __shfl_xor(tmax, 16));
                tmax = fmaxf(tmax, __shfl_xor(tmax, 32));
                float mnew  = fmaxf(m_[mb], tmax);
                float alpha = __expf(m_[mb] - mnew);
                float rsum = 0.f;
                #pragma unroll
                for (int kk = 0; kk < 2; ++kk)
                    #pragma unroll
                    for (int r = 0; r < 4; ++r) {
                        float p = __expf(s[kk][r] - mnew);
                        s[kk][r] = p;
                        rsum += p;
                    }
                rsum += __shfl_xor(rsum, 16);
                rsum += __shfl_xor(rsum, 32);
                l_[mb] = l_[mb] * alpha + rsum;
                m_[mb] = mnew;

                // P -> per-wave LDS (no barrier needed: same-wave DS ordering)
                #pragma unroll
                for (int kk = 0; kk < 2; ++kk) {
                    union { uint2 u; unsigned short h[4]; } pu;
                    #pragma unroll
                    for (int r = 0; r < 4; ++r) pu.h[r] = f2bf(s[kk][r]);
                    *(uint2*)&Pl[w][ql][kk * 16 + quad * 4] = pu.u;
                }

                // rescale O rows (row q = quad*4+r in C-layout)
                #pragma unroll
                for (int r = 0; r < 4; ++r) {
                    float ar = __shfl(alpha, quad * 4 + r);
                    #pragma unroll
                    for (int n = 0; n < 8; ++n) acc[mb][n][r] *= ar;
                }

                bf16x8 pf = *(const bf16x8*)&Pl[w][ql][quad * 8];
                #pragma unroll
                for (int n = 0; n < 8; ++n)
                    acc[mb][n] = __builtin_amdgcn_mfma_f32_16x16x32_bf16(pf, vf[n], acc[mb][n], 0, 0, 0);
            }
        }

        if (t + 1 < ntile) store_tile(buf ^ 1);  // vmcnt wait lands here, after compute
    }

    // ---- epilogue: O / l ----
    #pragma unroll
    for (int mb = 0; mb < 2; ++mb) {
        #pragma unroll
        for (int r = 0; r < 4; ++r) {
            float lr = __shfl(l_[mb], quad * 4 + r);
            float il = 1.0f / lr;
            long orow = base + (long)(qw0 + mb * 16 + quad * 4 + r) * DIM;
            #pragma unroll
            for (int n = 0; n < 8; ++n)
                out[orow + n * 16 + ql] = acc[mb][n][r] * il;
        }
    }
}

extern "C" void kernel_launch(void* const* d_in, const int* in_sizes, int n_in,
                              void* d_out, int out_size, void* d_ws, size_t ws_size,
                              hipStream_t stream) {
    const float* k = (const float*)d_in[0];
    const float* q = (const float*)d_in[1];
    const float* v = (const float*)d_in[2];
    float* o = (float*)d_out;

    unsigned short* kb = (unsigned short*)d_ws;
    unsigned short* vt = kb + (size_t)BHN * SEQ * DIM;

    const long ne = (long)BHN * SEQ * DIM;   // 16,777,216
    cvt_k <<<dim3(ne / (256 * 8)), dim3(256), 0, stream>>>(k, kb);
    cvt_vt<<<dim3(SEQ / 64, BHN),  dim3(256), 0, stream>>>(v, vt);

    dim3 grid(SEQ / BQ, BHN);
    attn_fwd<<<grid, dim3(256), 0, stream>>>(q, kb, vt, o);
}

// Round 3
// 454.835 us; speedup vs baseline: 1.7660x; 1.7660x over previous
//
#include <hip/hip_runtime.h>
#include <hip/hip_bf16.h>
#include <math.h>

#define BATCH 4
#define HEADS 16
#define SEQ   2048
#define DIM   128
#define BHN   (BATCH*HEADS)

#define BQ 128   // q rows per block
#define WQ 32    // q rows per wave (2 MFMA M-blocks)
#define KT 32    // k rows per stage/compute tile

typedef short bf16x8 __attribute__((ext_vector_type(8)));
typedef float f32x4  __attribute__((ext_vector_type(4)));

static __device__ __forceinline__ unsigned short f2bf(float f) {
    union { float f; unsigned u; } x; x.f = f;
    unsigned r = x.u + 0x7FFF + ((x.u >> 16) & 1);  // RNE
    return (unsigned short)(r >> 16);
}

// async 16B global -> LDS (no data VGPRs; LDS dest = wave-uniform base + lane*16)
static __device__ __forceinline__ void async_cp16(const unsigned short* g, unsigned short* l) {
    __builtin_amdgcn_global_load_lds(
        (const __attribute__((address_space(1))) unsigned int*)g,
        (__attribute__((address_space(3))) unsigned int*)l,
        16, 0, 0);
}

// ------------- fused fp32->bf16: K row-major, V transposed vt[bh][d][s] -------------
__global__ __launch_bounds__(256) void cvt_kv(
    const float* __restrict__ k, const float* __restrict__ v,
    unsigned short* __restrict__ kb, unsigned short* __restrict__ vt) {
    __shared__ unsigned short T[DIM][72];   // 64 s-rows transposed; 144B row stride
    const int bh = blockIdx.y;
    const int s0 = blockIdx.x * 64;
    const int t  = threadIdx.x;
    const long rbase = ((long)bh * SEQ + s0) * DIM;

    // K: 64 rows x 128 = 8192 elems, 32/thread
    #pragma unroll
    for (int u = 0; u < 2; ++u) {
        long e = rbase + (long)(t + u * 256) * 16;
        const float* src = k + e;
        unsigned short* dst = kb + e;
        #pragma unroll
        for (int h = 0; h < 2; ++h) {
            float4 a0 = *(const float4*)(src + h * 8);
            float4 a1 = *(const float4*)(src + h * 8 + 4);
            union { uint4 u4; unsigned short s[8]; } p;
            p.s[0]=f2bf(a0.x); p.s[1]=f2bf(a0.y); p.s[2]=f2bf(a0.z); p.s[3]=f2bf(a0.w);
            p.s[4]=f2bf(a1.x); p.s[5]=f2bf(a1.y); p.s[6]=f2bf(a1.z); p.s[7]=f2bf(a1.w);
            *(uint4*)(dst + h * 8) = p.u4;
        }
    }
    // V: stage transposed through LDS
    {
        const int r = t >> 2, i = t & 3;
        const float* src = v + rbase + (long)r * DIM + i * 32;
        #pragma unroll
        for (int j = 0; j < 8; ++j) {
            float4 x = *(const float4*)(src + j * 4);
            const int d = i * 32 + j * 4;
            T[d + 0][r] = f2bf(x.x); T[d + 1][r] = f2bf(x.y);
            T[d + 2][r] = f2bf(x.z); T[d + 3][r] = f2bf(x.w);
        }
    }
    __syncthreads();
    {
        const int d = t >> 1, h = t & 1;
        unsigned short* dst = vt + ((long)bh * DIM + d) * SEQ + s0 + h * 32;
        #pragma unroll
        for (int m = 0; m < 4; ++m)
            *(uint4*)(dst + m * 8) = *(const uint4*)&T[d][h * 32 + m * 8];
    }
}

// ---------------- flash attention ----------------
__global__ __launch_bounds__(256, 2) void attn_fwd(
    const float* __restrict__ qg,
    const unsigned short* __restrict__ kb,
    const unsigned short* __restrict__ vtg,
    float* __restrict__ out) {

    // Unpadded (global_load_lds-compatible); XOR chunk swizzle kills bank conflicts.
    __shared__ unsigned short Kt[2][KT][DIM];    // 2 x 32 x 128 (8 KB each)
    __shared__ unsigned short Vt[2][DIM][KT];    // 2 x 128 x 32 (8 KB each)
    __shared__ unsigned short Pl[4][16][KT + 8]; // per-wave P tile [q][k], padded (ds_write path)

    const int tid  = threadIdx.x;
    const int w    = tid >> 6;
    const int lane = tid & 63;
    const int quad = lane >> 4;
    const int ql   = lane & 15;

    const int bh  = blockIdx.y;
    const int xb  = gridDim.x - 1 - blockIdx.x;    // long (diagonal-heavy) blocks first
    const int qb0 = xb * BQ;
    const int qw0 = qb0 + w * WQ;

    const long base = (long)bh * SEQ * DIM;
    const float scale = 0.08838834764831845f;      // 1/sqrt(128), folded into Q

    // ---- Q fragments (B-operand for Sc = K*Q^T), pre-scaled ----
    bf16x8 qf[2][4];
    #pragma unroll
    for (int mb = 0; mb < 2; ++mb) {
        const float* qr = qg + base + (long)(qw0 + mb * 16 + ql) * DIM;
        #pragma unroll
        for (int c = 0; c < 4; ++c) {
            const float* p = qr + c * 32 + quad * 8;
            float4 x = *(const float4*)(p);
            float4 y = *(const float4*)(p + 4);
            union { bf16x8 v; unsigned short s[8]; } u;
            u.s[0]=f2bf(x.x*scale); u.s[1]=f2bf(x.y*scale);
            u.s[2]=f2bf(x.z*scale); u.s[3]=f2bf(x.w*scale);
            u.s[4]=f2bf(y.x*scale); u.s[5]=f2bf(y.y*scale);
            u.s[6]=f2bf(y.z*scale); u.s[7]=f2bf(y.w*scale);
            qf[mb][c] = u.v;
        }
    }

    f32x4 acc[2][8];
    #pragma unroll
    for (int mb = 0; mb < 2; ++mb)
        #pragma unroll
        for (int n = 0; n < 8; ++n)
            acc[mb][n] = (f32x4){0.f, 0.f, 0.f, 0.f};

    float m_[2] = {-INFINITY, -INFINITY};
    float l_[2] = {0.f, 0.f};

    // async stage of one 32-k tile into buffer `buf` (4 DMA/thread, 0 data VGPRs)
    auto stage = [&](int buf, int k0) {
        #pragma unroll
        for (int i = 0; i < 2; ++i) {
            const int idx = tid + i * 256;          // chunk id, 512 x 16B per tensor
            // K: row r, lds chunk (idx&15) holds global chunk (idx&15)^(r&15)
            const int r   = idx >> 4;
            const int chg = (idx & 15) ^ (r & 15);
            async_cp16(kb + base + (long)(k0 + r) * DIM + chg * 8,
                       &Kt[buf][0][0] + ((tid >> 6) * 64 + i * 256) * 8);
            // V: row d, lds chunk (idx&3) holds global chunk (idx&3)^((d>>1)&3)
            const int d   = idx >> 2;
            const int cvg = (idx & 3) ^ ((d >> 1) & 3);
            async_cp16(vtg + base + (long)d * SEQ + k0 + cvg * 8,
                       &Vt[buf][0][0] + ((tid >> 6) * 64 + i * 256) * 8);
        }
    };

    const int ntile = (qb0 + BQ) / KT;

    stage(0, 0);

    for (int t = 0; t < ntile; ++t) {
        const int buf = t & 1;
        const int k0  = t * KT;
        __syncthreads();   // vmcnt(0) drain: tile t resident; prev readers of other buf done

        if (t + 1 < ntile) stage(buf ^ 1, k0 + KT);   // in flight during compute of tile t

        const bool active = (k0 < qw0 + WQ);
        if (active) {
            // ---- Sc = K * Q^T  (rows=k, cols=q) ----
            f32x4 sacc[2][2];
            #pragma unroll
            for (int mb = 0; mb < 2; ++mb)
                #pragma unroll
                for (int kk = 0; kk < 2; ++kk)
                    sacc[mb][kk] = (f32x4){0.f, 0.f, 0.f, 0.f};
            #pragma unroll
            for (int c = 0; c < 4; ++c) {
                const int sw = ((c * 4 + quad) ^ ql) * 8;   // swizzled chunk offset
                bf16x8 kf0 = *(const bf16x8*)&Kt[buf][ql]     [sw];
                bf16x8 kf1 = *(const bf16x8*)&Kt[buf][16 + ql][sw];
                #pragma unroll
                for (int mb = 0; mb < 2; ++mb) {
                    sacc[mb][0] = __builtin_amdgcn_mfma_f32_16x16x32_bf16(kf0, qf[mb][c], sacc[mb][0], 0, 0, 0);
                    sacc[mb][1] = __builtin_amdgcn_mfma_f32_16x16x32_bf16(kf1, qf[mb][c], sacc[mb][1], 0, 0, 0);
                }
            }

            // V fragments (swizzled)
            bf16x8 vf[8];
            #pragma unroll
            for (int n = 0; n < 8; ++n)
                vf[n] = *(const bf16x8*)&Vt[buf][n * 16 + ql][(quad ^ ((ql >> 1) & 3)) * 8];

            #pragma unroll
            for (int mb = 0; mb < 2; ++mb) {
                const int qrow   = qw0 + mb * 16 + ql;
                const bool needm = (k0 + KT - 1 > qw0 + mb * 16);  // wave-uniform
                float s[2][4];
                float tmax = -INFINITY;
                #pragma unroll
                for (int kk = 0; kk < 2; ++kk)
                    #pragma unroll
                    for (int r = 0; r < 4; ++r) {
                        float sv = sacc[mb][kk][r];
                        if (needm) {
                            int kg = k0 + kk * 16 + quad * 4 + r;
                            sv = (kg <= qrow) ? sv : -INFINITY;
                        }
                        s[kk][r] = sv;
                        tmax = fmaxf(tmax, sv);
                    }
                tmax = fmaxf(tmax, __shfl_xor(tmax, 16));
                tmax = fmaxf(tmax, __shfl_xor(tmax, 32));
                float mnew  = fmaxf(m_[mb], tmax);
                float alpha = __expf(m_[mb] - mnew);
                float rsum = 0.f;
                #pragma unroll
                for (int kk = 0; kk < 2; ++kk)
                    #pragma unroll
                    for (int r = 0; r < 4; ++r) {
                        float p = __expf(s[kk][r] - mnew);
                        s[kk][r] = p;
                        rsum += p;
                    }
                rsum += __shfl_xor(rsum, 16);
                rsum += __shfl_xor(rsum, 32);
                l_[mb] = l_[mb] * alpha + rsum;
                m_[mb] = mnew;

                // P -> per-wave LDS (same-wave DS ordering; no barrier)
                #pragma unroll
                for (int kk = 0; kk < 2; ++kk) {
                    union { uint2 u; unsigned short h[4]; } pu;
                    #pragma unroll
                    for (int r = 0; r < 4; ++r) pu.h[r] = f2bf(s[kk][r]);
                    *(uint2*)&Pl[w][ql][kk * 16 + quad * 4] = pu.u;
                }

                // rescale O rows (row q = quad*4+r in C-layout)
                #pragma unroll
                for (int r = 0; r < 4; ++r) {
                    float ar = __shfl(alpha, quad * 4 + r);
                    #pragma unroll
                    for (int n = 0; n < 8; ++n) acc[mb][n][r] *= ar;
                }

                bf16x8 pf = *(const bf16x8*)&Pl[w][ql][quad * 8];
                #pragma unroll
                for (int n = 0; n < 8; ++n)
                    acc[mb][n] = __builtin_amdgcn_mfma_f32_16x16x32_bf16(pf, vf[n], acc[mb][n], 0, 0, 0);
            }
        }
    }

    // ---- epilogue: O / l ----
    #pragma unroll
    for (int mb = 0; mb < 2; ++mb) {
        #pragma unroll
        for (int r = 0; r < 4; ++r) {
            float lr = __shfl(l_[mb], quad * 4 + r);
            float il = 1.0f / lr;
            long orow = base + (long)(qw0 + mb * 16 + quad * 4 + r) * DIM;
            #pragma unroll
            for (int n = 0; n < 8; ++n)
                out[orow + n * 16 + ql] = acc[mb][n][r] * il;
        }
    }
}

extern "C" void kernel_launch(void* const* d_in, const int* in_sizes, int n_in,
                              void* d_out, int out_size, void* d_ws, size_t ws_size,
                              hipStream_t stream) {
    const float* k = (const float*)d_in[0];
    const float* q = (const float*)d_in[1];
    const float* v = (const float*)d_in[2];
    float* o = (float*)d_out;

    unsigned short* kb = (unsigned short*)d_ws;
    unsigned short* vt = kb + (size_t)BHN * SEQ * DIM;

    cvt_kv<<<dim3(SEQ / 64, BHN), dim3(256), 0, stream>>>(k, v, kb, vt);

    dim3 grid(SEQ / BQ, BHN);
    attn_fwd<<<grid, dim3(256), 0, stream>>>(q, kb, vt, o);
}